// Round 1
// baseline (197.866 us; speedup 1.0000x reference)
//
#include <hip/hip_runtime.h>
#include <stdint.h>

// Problem constants (match reference setup_inputs)
namespace {
constexpr int B = 4, P = 4, V = 4096, M = 2048;
constexpr int BP = B * P;
constexpr float BIGF = 1e10f;
constexpr int TX = V / 256;   // 16 x-tiles (compacted-vertex tiles)
constexpr int TY = M / 256;   // 8 y-tiles (edge-point tiles)
}

// ---------------------------------------------------------------------------
// prep: detect boundary_mask layout, project vertices, compact masked ones
// per (b,p), count them, zero the accumulators.
// grid = BP blocks (one per (b,p)), 256 threads.
// ---------------------------------------------------------------------------
__global__ __launch_bounds__(256) void prep_kernel(
    const float* __restrict__ vertices,    // (B,V,3)
    const float* __restrict__ projmats,    // (P,3,4)
    const uint8_t* __restrict__ maskraw,   // (B,P,V) unknown elem layout
    int* __restrict__ nvalid,              // (BP)
    float* __restrict__ sx,                // (BP)
    float* __restrict__ sy,                // (BP)
    float2* __restrict__ pts_c)            // (BP, V) compacted projected pts
{
    const int bp = blockIdx.x;
    const int b = bp / P, p = bp % P;
    const int tid = threadIdx.x;

    __shared__ int s_res[4];
    __shared__ int s_cnt;
    if (tid < 4) s_res[tid] = 0;
    if (tid == 0) s_cnt = 0;
    __syncthreads();

    // --- detect mask element layout by byte-residue pattern (mod 4) ---
    // uint8 bernoulli(0.3): nonzero bytes at every residue.
    // int32 0/1 (LE):       nonzero only at residue 0.
    // float32 0/1.0f (LE):  nonzero only at residues 2 (0x80) and 3 (0x3f).
    uint32_t loc[4] = {0u, 0u, 0u, 0u};
    const int NB = BP * V;  // 65536 bytes: valid under every candidate layout
    for (int i = tid * 16; i < NB; i += 256 * 16) {
        const uint32_t* w = (const uint32_t*)(maskraw + i);
        const uint32_t orw = w[0] | w[1] | w[2] | w[3];
        loc[0] |= orw & 0x000000FFu;
        loc[1] |= orw & 0x0000FF00u;
        loc[2] |= orw & 0x00FF0000u;
        loc[3] |= orw & 0xFF000000u;
    }
    #pragma unroll
    for (int j = 0; j < 4; ++j)
        if (loc[j]) atomicOr(&s_res[j], 1);
    __syncthreads();
    int layout;  // 0 = uint8/bool, 1 = int32, 2 = float32
    if (!s_res[1] && !s_res[2] && !s_res[3]) layout = 1;
    else if (!s_res[0] && !s_res[1])         layout = 2;
    else                                      layout = 0;

    // --- projection matrix for this view (uniform per block) ---
    float mm[12];
    #pragma unroll
    for (int j = 0; j < 12; ++j) mm[j] = projmats[p * 12 + j];

    // --- project + compact masked vertices (order irrelevant: min/sum) ---
    for (int v = tid; v < V; v += 256) {
        const int mi = bp * V + v;
        bool msk;
        if (layout == 0)      msk = maskraw[mi] != 0;
        else if (layout == 1) msk = ((const int*)maskraw)[mi] != 0;
        else                  msk = ((const float*)maskraw)[mi] != 0.0f;
        if (msk) {
            const float x = vertices[(b * V + v) * 3 + 0];
            const float y = vertices[(b * V + v) * 3 + 1];
            const float z = vertices[(b * V + v) * 3 + 2];
            const float u  = mm[0]*x + mm[1]*y + mm[2]*z  + mm[3];
            const float vv = mm[4]*x + mm[5]*y + mm[6]*z  + mm[7];
            const float w  = mm[8]*x + mm[9]*y + mm[10]*z + mm[11];
            const int idx = atomicAdd(&s_cnt, 1);
            pts_c[bp * V + idx] = make_float2(u / w, vv / w);
        }
    }
    __syncthreads();
    if (tid == 0) {
        nvalid[bp] = s_cnt;
        sx[bp] = 0.0f;
        sy[bp] = 0.0f;
    }
}

// ---------------------------------------------------------------------------
// fused chamfer: X-role blocks compute sum_{masked v} min_{m<len} d2;
// Y-role blocks compute sum_{m<len} min_{masked v} d2.
// grid = (BP, TX+TY), 256 threads.
// ---------------------------------------------------------------------------
__global__ __launch_bounds__(256) void chamfer_kernel(
    const float* __restrict__ edgemaps,    // (B,P,M,2)
    const int* __restrict__ elen,          // (B,P)
    const int* __restrict__ nvalid,        // (BP)
    const float2* __restrict__ pts_c,      // (BP,V)
    float* __restrict__ sx,
    float* __restrict__ sy)
{
    const int bp  = blockIdx.x;
    const int role = blockIdx.y;
    const int tid = threadIdx.x;
    const int len = elen[bp];
    const int nv  = nvalid[bp];

    __shared__ float2 s_buf[V];   // 32 KiB (X uses first M entries)

    float val = 0.0f;
    const bool isX = (role < TX);
    if (isX) {
        const int t = role;
        if (t * 256 >= nv) return;   // block-uniform early exit
        // stage the full edgemap slice (M float2) into LDS, float4 loads
        const float4* eg = (const float4*)(edgemaps + (size_t)bp * M * 2);
        float4* sp = (float4*)s_buf;
        for (int i = tid; i < M / 2; i += 256) sp[i] = eg[i];
        __syncthreads();
        const int ci = t * 256 + tid;
        if (ci < nv) {
            const float2 pt = pts_c[bp * V + ci];
            const float px = pt.x, py = pt.y;
            float mn = BIGF;
            #pragma unroll 8
            for (int m = 0; m < len; ++m) {
                const float2 e = s_buf[m];      // wave-uniform broadcast
                const float dx = px - e.x;
                const float dy = py - e.y;
                const float d = dx * dx + dy * dy;
                mn = fminf(mn, d);
            }
            val = fmaxf(mn, 0.0f);
        }
    } else {
        const int t = role - TX;
        if (t * 256 >= len) return;  // block-uniform early exit
        for (int i = tid; i < nv; i += 256) s_buf[i] = pts_c[bp * V + i];
        __syncthreads();
        const int m = t * 256 + tid;
        if (m < len) {
            const float2 e = ((const float2*)edgemaps)[(size_t)bp * M + m];
            const float ex = e.x, ey = e.y;
            float mn = BIGF;   // stays 1e10 if nv==0 -> matches reference BIG
            #pragma unroll 8
            for (int i = 0; i < nv; ++i) {
                const float2 pt = s_buf[i];     // wave-uniform broadcast
                const float dx = ex - pt.x;
                const float dy = ey - pt.y;
                const float d = dx * dx + dy * dy;
                mn = fminf(mn, d);
            }
            val = fmaxf(mn, 0.0f);
        }
    }

    // per-wave reduce (64 lanes) then one atomic per wave
    #pragma unroll
    for (int off = 32; off > 0; off >>= 1)
        val += __shfl_down(val, off, 64);
    if ((tid & 63) == 0)
        atomicAdd(isX ? &sx[bp] : &sy[bp], val);
}

// ---------------------------------------------------------------------------
// finalize: out[b] = mean_p( sx/max(nvalid,1) + sy/max(len,1) )
// ---------------------------------------------------------------------------
__global__ void finalize_kernel(
    const float* __restrict__ sx, const float* __restrict__ sy,
    const int* __restrict__ nvalid, const int* __restrict__ elen,
    float* __restrict__ out)
{
    const int b = threadIdx.x;
    if (b < B) {
        float acc = 0.0f;
        #pragma unroll
        for (int p = 0; p < P; ++p) {
            const int bp = b * P + p;
            const float xl = fmaxf((float)nvalid[bp], 1.0f);
            const float yl = fmaxf((float)elen[bp], 1.0f);
            acc += sx[bp] / xl + sy[bp] / yl;
        }
        out[b] = acc * (1.0f / P);
    }
}

extern "C" void kernel_launch(void* const* d_in, const int* in_sizes, int n_in,
                              void* d_out, int out_size, void* d_ws, size_t ws_size,
                              hipStream_t stream)
{
    const float*   vertices = (const float*)d_in[0];
    const float*   projmats = (const float*)d_in[1];
    const float*   edgemaps = (const float*)d_in[2];
    const uint8_t* maskraw  = (const uint8_t*)d_in[3];
    const int*     elen     = (const int*)d_in[4];
    float* out = (float*)d_out;

    // workspace layout: [nvalid:16 int][sx:16 f][sy:16 f] ... pad ... [pts_c: BP*V float2]
    int*    nvalid = (int*)d_ws;
    float*  sx     = (float*)d_ws + 16;
    float*  sy     = (float*)d_ws + 32;
    float2* pts_c  = (float2*)((char*)d_ws + 256);

    prep_kernel<<<BP, 256, 0, stream>>>(vertices, projmats, maskraw,
                                        nvalid, sx, sy, pts_c);
    chamfer_kernel<<<dim3(BP, TX + TY), 256, 0, stream>>>(edgemaps, elen,
                                                          nvalid, pts_c, sx, sy);
    finalize_kernel<<<1, 64, 0, stream>>>(sx, sy, nvalid, elen, out);
}

// Round 2
// 127.749 us; speedup vs baseline: 1.5489x; 1.5489x over previous
//
#include <hip/hip_runtime.h>
#include <stdint.h>

// Problem constants (match reference setup_inputs)
namespace {
constexpr int B = 4, P = 4, V = 4096, M = 2048;
constexpr int BP = B * P;
constexpr float BIGF = 1e10f;
constexpr int TPB  = 128;         // threads per chamfer block
constexpr int TILE = 256;         // outer points per block (2 per thread)
constexpr int TXn = V / TILE;     // 16 x-role tiles
constexpr int TYn = M / TILE;     // 8 y-role tiles
constexpr int CHUNK = 2048;       // inner elements staged per LDS pass
}

// ---------------------------------------------------------------------------
// prep: detect boundary_mask layout, project vertices, compact masked ones
// per (b,p) via wave-ballot prefix (1 LDS atomic per wave-iter), count them,
// zero accumulators.  grid = BP blocks, 256 threads.
// ---------------------------------------------------------------------------
__global__ __launch_bounds__(256) void prep_kernel(
    const float* __restrict__ vertices,    // (B,V,3)
    const float* __restrict__ projmats,    // (P,3,4)
    const uint8_t* __restrict__ maskraw,   // (B,P,V) unknown elem layout
    int* __restrict__ nvalid,              // (BP)
    float* __restrict__ sx,                // (BP)
    float* __restrict__ sy,                // (BP)
    float2* __restrict__ pts_c)            // (BP, V) compacted projected pts
{
    const int bp = blockIdx.x;
    const int b = bp / P, p = bp % P;
    const int tid = threadIdx.x;
    const int lane = tid & 63;

    __shared__ int s_res[4];
    __shared__ int s_cnt;
    if (tid < 4) s_res[tid] = 0;
    if (tid == 0) s_cnt = 0;
    __syncthreads();

    // --- detect mask element layout by byte-residue pattern (mod 4) ---
    // uint8 bernoulli(0.3): nonzero bytes at every residue.
    // int32 0/1 (LE):       nonzero only at residue 0.
    // float32 0/1.0f (LE):  nonzero only at residues 2 (0x80) and 3 (0x3f).
    uint32_t loc[4] = {0u, 0u, 0u, 0u};
    const int NB = BP * V;  // 65536 bytes: valid under every candidate layout
    for (int i = tid * 16; i < NB; i += 256 * 16) {
        const uint32_t* w = (const uint32_t*)(maskraw + i);
        const uint32_t orw = w[0] | w[1] | w[2] | w[3];
        loc[0] |= orw & 0x000000FFu;
        loc[1] |= orw & 0x0000FF00u;
        loc[2] |= orw & 0x00FF0000u;
        loc[3] |= orw & 0xFF000000u;
    }
    #pragma unroll
    for (int j = 0; j < 4; ++j)
        if (loc[j]) atomicOr(&s_res[j], 1);
    __syncthreads();
    int layout;  // 0 = uint8/bool, 1 = int32, 2 = float32
    if (!s_res[1] && !s_res[2] && !s_res[3]) layout = 1;
    else if (!s_res[0] && !s_res[1])         layout = 2;
    else                                      layout = 0;

    // --- projection matrix for this view (uniform per block) ---
    float mm[12];
    #pragma unroll
    for (int j = 0; j < 12; ++j) mm[j] = projmats[p * 12 + j];

    // --- project + compact masked vertices (ballot-prefix compaction) ---
    for (int v = tid; v < V; v += 256) {
        const int mi = bp * V + v;
        bool msk;
        if (layout == 0)      msk = maskraw[mi] != 0;
        else if (layout == 1) msk = ((const int*)maskraw)[mi] != 0;
        else                  msk = ((const float*)maskraw)[mi] != 0.0f;

        const unsigned long long ball = __ballot(msk);
        const int cnt = __popcll(ball);
        int base = 0;
        if (lane == 0 && cnt) base = atomicAdd(&s_cnt, cnt);
        base = __shfl(base, 0, 64);
        if (msk) {
            const float x = vertices[(b * V + v) * 3 + 0];
            const float y = vertices[(b * V + v) * 3 + 1];
            const float z = vertices[(b * V + v) * 3 + 2];
            const float u  = mm[0]*x + mm[1]*y + mm[2]*z  + mm[3];
            const float vv = mm[4]*x + mm[5]*y + mm[6]*z  + mm[7];
            const float w  = mm[8]*x + mm[9]*y + mm[10]*z + mm[11];
            const int off = __popcll(ball & ((1ull << lane) - 1ull));
            const float rw = 1.0f / w;
            pts_c[bp * V + base + off] = make_float2(u * rw, vv * rw);
        }
    }
    __syncthreads();
    if (tid == 0) {
        nvalid[bp] = s_cnt;
        sx[bp] = 0.0f;
        sy[bp] = 0.0f;
    }
}

// ---------------------------------------------------------------------------
// fused chamfer, norm-form: d2 = (en - 2ex*px - 2ey*py) + pn, 3 VALU/pair.
// Each thread owns 2 outer points (2 independent min chains -> ILP), one
// ds_read_b128 per inner element serves both.
// grid = (BP, TXn+TYn), 128 threads.
// ---------------------------------------------------------------------------
__global__ __launch_bounds__(TPB) void chamfer_kernel(
    const float* __restrict__ edgemaps,    // (B,P,M,2)
    const int* __restrict__ elen,          // (B,P)
    const int* __restrict__ nvalid,        // (BP)
    const float2* __restrict__ pts_c,      // (BP,V)
    float* __restrict__ sx,
    float* __restrict__ sy)
{
    const int bp   = blockIdx.x;
    const int role = blockIdx.y;
    const int tid  = threadIdx.x;
    const int len  = elen[bp];
    const int nv   = nvalid[bp];

    __shared__ float4 sb[CHUNK];   // 32 KiB: (x, y, norm, pad)

    float val = 0.0f;
    const bool isX = (role < TXn);

    if (isX) {
        const int t = role;
        if (t * TILE >= nv) return;            // block-uniform early exit

        // my 2 outer points (compacted projected vertices)
        const int ci0 = t * TILE + tid;
        const int ci1 = ci0 + TPB;
        const float2 p0 = (ci0 < nv) ? pts_c[bp * V + ci0] : make_float2(0.f, 0.f);
        const float2 p1 = (ci1 < nv) ? pts_c[bp * V + ci1] : make_float2(0.f, 0.f);
        const float a0 = -2.0f * p0.x, b0 = -2.0f * p0.y;
        const float a1 = -2.0f * p1.x, b1 = -2.0f * p1.y;
        const float pn0 = p0.x * p0.x + p0.y * p0.y;
        const float pn1 = p1.x * p1.x + p1.y * p1.y;

        // stage edgemap slice with norms into LDS
        const float2* eg = (const float2*)(edgemaps) + (size_t)bp * M;
        for (int i = tid; i < len; i += TPB) {
            const float2 e = eg[i];
            sb[i] = make_float4(e.x, e.y, e.x * e.x + e.y * e.y, 0.f);
        }
        __syncthreads();

        float mn0 = BIGF, mn1 = BIGF;
        #pragma unroll 4
        for (int m = 0; m < len; ++m) {
            const float4 e = sb[m];            // wave-uniform broadcast b128
            const float q0 = fmaf(e.x, a0, fmaf(e.y, b0, e.z));
            const float q1 = fmaf(e.x, a1, fmaf(e.y, b1, e.z));
            mn0 = fminf(mn0, q0);
            mn1 = fminf(mn1, q1);
        }
        // clamp commutes with min; fp32 absorbs BIG + pn -> BIG exactly
        const float v0 = (ci0 < nv) ? fmaxf(mn0 + pn0, 0.0f) : 0.0f;
        const float v1 = (ci1 < nv) ? fmaxf(mn1 + pn1, 0.0f) : 0.0f;
        val = v0 + v1;
    } else {
        const int t = role - TXn;
        if (t * TILE >= len) return;           // block-uniform early exit

        // my 2 outer points (edge-map points)
        const int m0 = t * TILE + tid;
        const int m1 = m0 + TPB;
        const float2* eg = (const float2*)(edgemaps) + (size_t)bp * M;
        const float2 e0 = (m0 < len) ? eg[m0] : make_float2(0.f, 0.f);
        const float2 e1 = (m1 < len) ? eg[m1] : make_float2(0.f, 0.f);
        const float a0 = -2.0f * e0.x, b0 = -2.0f * e0.y;
        const float a1 = -2.0f * e1.x, b1 = -2.0f * e1.y;
        const float en0 = e0.x * e0.x + e0.y * e0.y;
        const float en1 = e1.x * e1.x + e1.y * e1.y;

        float mn0 = BIGF, mn1 = BIGF;
        for (int base = 0; base < nv; base += CHUNK) {
            const int cn = min(nv - base, CHUNK);
            __syncthreads();                    // safe re-stage boundary
            const float2* pc = pts_c + (size_t)bp * V + base;
            for (int i = tid; i < cn; i += TPB) {
                const float2 q = pc[i];
                sb[i] = make_float4(q.x, q.y, q.x * q.x + q.y * q.y, 0.f);
            }
            __syncthreads();
            #pragma unroll 4
            for (int i = 0; i < cn; ++i) {
                const float4 s = sb[i];        // wave-uniform broadcast b128
                const float q0 = fmaf(s.x, a0, fmaf(s.y, b0, s.z));
                const float q1 = fmaf(s.x, a1, fmaf(s.y, b1, s.z));
                mn0 = fminf(mn0, q0);
                mn1 = fminf(mn1, q1);
            }
        }
        const float v0 = (m0 < len) ? fmaxf(mn0 + en0, 0.0f) : 0.0f;
        const float v1 = (m1 < len) ? fmaxf(mn1 + en1, 0.0f) : 0.0f;
        val = v0 + v1;
    }

    // per-wave reduce (64 lanes) then one atomic per wave
    #pragma unroll
    for (int off = 32; off > 0; off >>= 1)
        val += __shfl_down(val, off, 64);
    if ((tid & 63) == 0)
        atomicAdd(isX ? &sx[bp] : &sy[bp], val);
}

// ---------------------------------------------------------------------------
// finalize: out[b] = mean_p( sx/max(nvalid,1) + sy/max(len,1) )
// ---------------------------------------------------------------------------
__global__ void finalize_kernel(
    const float* __restrict__ sx, const float* __restrict__ sy,
    const int* __restrict__ nvalid, const int* __restrict__ elen,
    float* __restrict__ out)
{
    const int b = threadIdx.x;
    if (b < B) {
        float acc = 0.0f;
        #pragma unroll
        for (int p = 0; p < P; ++p) {
            const int bp = b * P + p;
            const float xl = fmaxf((float)nvalid[bp], 1.0f);
            const float yl = fmaxf((float)elen[bp], 1.0f);
            acc += sx[bp] / xl + sy[bp] / yl;
        }
        out[b] = acc * (1.0f / P);
    }
}

extern "C" void kernel_launch(void* const* d_in, const int* in_sizes, int n_in,
                              void* d_out, int out_size, void* d_ws, size_t ws_size,
                              hipStream_t stream)
{
    const float*   vertices = (const float*)d_in[0];
    const float*   projmats = (const float*)d_in[1];
    const float*   edgemaps = (const float*)d_in[2];
    const uint8_t* maskraw  = (const uint8_t*)d_in[3];
    const int*     elen     = (const int*)d_in[4];
    float* out = (float*)d_out;

    // workspace: [nvalid:16 int][sx:16 f][sy:16 f] ... pad ... [pts_c: BP*V float2]
    int*    nvalid = (int*)d_ws;
    float*  sx     = (float*)d_ws + 16;
    float*  sy     = (float*)d_ws + 32;
    float2* pts_c  = (float2*)((char*)d_ws + 256);

    prep_kernel<<<BP, 256, 0, stream>>>(vertices, projmats, maskraw,
                                        nvalid, sx, sy, pts_c);
    chamfer_kernel<<<dim3(BP, TXn + TYn), TPB, 0, stream>>>(edgemaps, elen,
                                                            nvalid, pts_c, sx, sy);
    finalize_kernel<<<1, 64, 0, stream>>>(sx, sy, nvalid, elen, out);
}

// Round 3
// 113.608 us; speedup vs baseline: 1.7417x; 1.1245x over previous
//
#include <hip/hip_runtime.h>
#include <stdint.h>

// Problem constants (match reference setup_inputs)
namespace {
constexpr int B = 4, P = 4, V = 4096, M = 2048;
constexpr int BP = B * P;
constexpr float BIGF = 1e10f;
constexpr int TPB = 64;        // one wave per chamfer block
constexpr int C   = 8;         // outer points (independent min chains) per thread
constexpr int OT  = TPB * C;   // 512 outer points per tile
constexpr int IC  = 256;       // inner elements staged per block
constexpr int XT_O = V / OT;   // 8 outer tiles (x-role)
constexpr int XT_I = M / IC;   // 8 inner chunks (x-role)
constexpr int YT_O = M / OT;   // 4 outer tiles (y-role)
constexpr int YT_I = V / IC;   // 16 inner chunks (y-role)
constexpr int XROLES = XT_O * XT_I;  // 64
constexpr int YROLES = YT_O * YT_I;  // 64
}

// ---------------------------------------------------------------------------
// prep: detect boundary_mask layout, project vertices, compact masked ones
// per (b,p) via wave-ballot prefix, count them, init per-point min arrays.
// grid = BP blocks, 256 threads.
// ---------------------------------------------------------------------------
__global__ __launch_bounds__(256) void prep_kernel(
    const float* __restrict__ vertices,    // (B,V,3)
    const float* __restrict__ projmats,    // (P,3,4)
    const uint8_t* __restrict__ maskraw,   // (B,P,V) unknown elem layout
    int* __restrict__ nvalid,              // (BP)
    float2* __restrict__ pts_c,            // (BP, V) compacted projected pts
    unsigned* __restrict__ pmx,            // (BP, V) per-compacted-vertex min
    unsigned* __restrict__ pmy)            // (BP, M) per-edge-point min
{
    const int bp = blockIdx.x;
    const int b = bp / P, p = bp % P;
    const int tid = threadIdx.x;
    const int lane = tid & 63;

    __shared__ int s_res[4];
    __shared__ int s_cnt;
    if (tid < 4) s_res[tid] = 0;
    if (tid == 0) s_cnt = 0;
    __syncthreads();

    // init per-point min arrays to BIG (re-done every call; ws is re-poisoned)
    const unsigned bigbits = __float_as_uint(BIGF);
    for (int i = tid; i < V; i += 256) pmx[(size_t)bp * V + i] = bigbits;
    for (int i = tid; i < M; i += 256) pmy[(size_t)bp * M + i] = bigbits;

    // --- detect mask element layout by byte-residue pattern (mod 4) ---
    // uint8 bernoulli(0.3): nonzero bytes at every residue.
    // int32 0/1 (LE):       nonzero only at residue 0.
    // float32 0/1.0f (LE):  nonzero only at residues 2 (0x80) and 3 (0x3f).
    uint32_t loc[4] = {0u, 0u, 0u, 0u};
    const int NB = BP * V;  // 65536 bytes: valid under every candidate layout
    for (int i = tid * 16; i < NB; i += 256 * 16) {
        const uint32_t* w = (const uint32_t*)(maskraw + i);
        const uint32_t orw = w[0] | w[1] | w[2] | w[3];
        loc[0] |= orw & 0x000000FFu;
        loc[1] |= orw & 0x0000FF00u;
        loc[2] |= orw & 0x00FF0000u;
        loc[3] |= orw & 0xFF000000u;
    }
    #pragma unroll
    for (int j = 0; j < 4; ++j)
        if (loc[j]) atomicOr(&s_res[j], 1);
    __syncthreads();
    int layout;  // 0 = uint8/bool, 1 = int32, 2 = float32
    if (!s_res[1] && !s_res[2] && !s_res[3]) layout = 1;
    else if (!s_res[0] && !s_res[1])         layout = 2;
    else                                      layout = 0;

    // --- projection matrix for this view (uniform per block) ---
    float mm[12];
    #pragma unroll
    for (int j = 0; j < 12; ++j) mm[j] = projmats[p * 12 + j];

    // --- project + compact masked vertices (ballot-prefix compaction) ---
    for (int v = tid; v < V; v += 256) {
        const int mi = bp * V + v;
        bool msk;
        if (layout == 0)      msk = maskraw[mi] != 0;
        else if (layout == 1) msk = ((const int*)maskraw)[mi] != 0;
        else                  msk = ((const float*)maskraw)[mi] != 0.0f;

        const unsigned long long ball = __ballot(msk);
        const int cnt = __popcll(ball);
        int base = 0;
        if (lane == 0 && cnt) base = atomicAdd(&s_cnt, cnt);
        base = __shfl(base, 0, 64);
        if (msk) {
            const float x = vertices[(b * V + v) * 3 + 0];
            const float y = vertices[(b * V + v) * 3 + 1];
            const float z = vertices[(b * V + v) * 3 + 2];
            const float u  = mm[0]*x + mm[1]*y + mm[2]*z  + mm[3];
            const float vv = mm[4]*x + mm[5]*y + mm[6]*z  + mm[7];
            const float w  = mm[8]*x + mm[9]*y + mm[10]*z + mm[11];
            const int off = __popcll(ball & ((1ull << lane) - 1ull));
            const float rw = 1.0f / w;
            pts_c[(size_t)bp * V + base + off] = make_float2(u * rw, vv * rw);
        }
    }
    __syncthreads();
    if (tid == 0) nvalid[bp] = s_cnt;
}

// ---------------------------------------------------------------------------
// chamfer partial-min: unified X/Y roles, single-wave blocks, 8 chains/thread,
// inner chunk of 256 staged in LDS as (x, y, |e|^2, pad).
//   d2 = (|e|^2 - 2 e.x*px - 2 e.y*py) + |p|^2  -> 3 VALU/pair.
// Partial mins merged via uint-encoded atomicMin (all values >= 0).
// grid = (BP, XROLES + YROLES), 64 threads.
// ---------------------------------------------------------------------------
__global__ __launch_bounds__(TPB) void chamfer_kernel(
    const float* __restrict__ edgemaps,    // (B,P,M,2)
    const int* __restrict__ elen,          // (B,P)
    const int* __restrict__ nvalid,        // (BP)
    const float2* __restrict__ pts_c,      // (BP,V)
    unsigned* __restrict__ pmx,            // (BP,V)
    unsigned* __restrict__ pmy)            // (BP,M)
{
    const int bp = blockIdx.x;
    int role = blockIdx.y;
    const int tid = threadIdx.x;
    const int len = elen[bp];
    const int nv  = nvalid[bp];

    const float2* outer;
    const float2* inner;
    int outer_lim, inner_lim, obase, ibase;
    unsigned* pmin;

    if (role < XROLES) {
        const int ot = role / XT_I, it = role % XT_I;
        obase = ot * OT; ibase = it * IC;
        if (obase >= nv || ibase >= len) return;   // block-uniform exit
        outer = pts_c + (size_t)bp * V;            outer_lim = nv;
        inner = (const float2*)edgemaps + (size_t)bp * M; inner_lim = len;
        pmin  = pmx + (size_t)bp * V;
    } else {
        role -= XROLES;
        const int ot = role / YT_I, it = role % YT_I;
        obase = ot * OT; ibase = it * IC;
        if (obase >= len || ibase >= nv) return;   // block-uniform exit
        outer = (const float2*)edgemaps + (size_t)bp * M; outer_lim = len;
        inner = pts_c + (size_t)bp * V;            inner_lim = nv;
        pmin  = pmy + (size_t)bp * M;
    }
    const int cnt = min(IC, inner_lim - ibase);

    __shared__ float4 sb[IC];   // 4 KiB
    for (int i = tid; i < cnt; i += TPB) {
        const float2 e = inner[ibase + i];
        sb[i] = make_float4(e.x, e.y, fmaf(e.x, e.x, e.y * e.y), 0.f);
    }
    __syncthreads();

    float ax[C], ay[C], pn[C], mn[C];
    bool act[C];
    #pragma unroll
    for (int c = 0; c < C; ++c) {
        const int idx = obase + c * TPB + tid;
        act[c] = idx < outer_lim;
        const float2 pt = act[c] ? outer[idx] : make_float2(0.f, 0.f);
        ax[c] = -2.0f * pt.x;
        ay[c] = -2.0f * pt.y;
        pn[c] = fmaf(pt.x, pt.x, pt.y * pt.y);
        mn[c] = BIGF;
    }

    #pragma unroll 2
    for (int i = 0; i < cnt; ++i) {
        const float4 s = sb[i];            // wave-uniform broadcast b128
        #pragma unroll
        for (int c = 0; c < C; ++c)
            mn[c] = fminf(mn[c], fmaf(s.x, ax[c], fmaf(s.y, ay[c], s.z)));
    }

    #pragma unroll
    for (int c = 0; c < C; ++c) {
        if (act[c]) {
            const float v = fmaxf(mn[c] + pn[c], 0.0f);  // clamp commutes w/ min
            atomicMin(&pmin[obase + c * TPB + tid], __float_as_uint(v));
        }
    }
}

// ---------------------------------------------------------------------------
// finalize: out[b] = mean_p( sum(pmx[0..nv))/max(nv,1) + sum(pmy[0..len))/max(len,1) )
// grid = B blocks, 256 threads.
// ---------------------------------------------------------------------------
__global__ __launch_bounds__(256) void finalize_kernel(
    const unsigned* __restrict__ pmx, const unsigned* __restrict__ pmy,
    const int* __restrict__ nvalid, const int* __restrict__ elen,
    float* __restrict__ out)
{
    const int b = blockIdx.x;
    const int tid = threadIdx.x;
    __shared__ float s_x[4], s_y[4];
    float acc = 0.0f;
    for (int p = 0; p < P; ++p) {
        const int bp = b * P + p;
        const int nv  = nvalid[bp];
        const int len = elen[bp];
        float lx = 0.0f, ly = 0.0f;
        for (int i = tid; i < nv; i += 256)  lx += __uint_as_float(pmx[(size_t)bp * V + i]);
        for (int i = tid; i < len; i += 256) ly += __uint_as_float(pmy[(size_t)bp * M + i]);
        #pragma unroll
        for (int off = 32; off > 0; off >>= 1) {
            lx += __shfl_down(lx, off, 64);
            ly += __shfl_down(ly, off, 64);
        }
        if ((tid & 63) == 0) { s_x[tid >> 6] = lx; s_y[tid >> 6] = ly; }
        __syncthreads();
        if (tid == 0) {
            const float sx = s_x[0] + s_x[1] + s_x[2] + s_x[3];
            const float sy = s_y[0] + s_y[1] + s_y[2] + s_y[3];
            acc += sx / fmaxf((float)nv, 1.0f) + sy / fmaxf((float)len, 1.0f);
        }
        __syncthreads();
    }
    if (tid == 0) out[b] = acc * (1.0f / P);
}

extern "C" void kernel_launch(void* const* d_in, const int* in_sizes, int n_in,
                              void* d_out, int out_size, void* d_ws, size_t ws_size,
                              hipStream_t stream)
{
    const float*   vertices = (const float*)d_in[0];
    const float*   projmats = (const float*)d_in[1];
    const float*   edgemaps = (const float*)d_in[2];
    const uint8_t* maskraw  = (const uint8_t*)d_in[3];
    const int*     elen     = (const int*)d_in[4];
    float* out = (float*)d_out;

    // workspace layout (bytes):
    //   [0,64)        nvalid (16 int)
    //   [256, +512K)  pts_c  (BP*V float2)
    //   then pmx (BP*V uint), pmy (BP*M uint)   -- total ~897 KB
    int*      nvalid = (int*)d_ws;
    float2*   pts_c  = (float2*)((char*)d_ws + 256);
    unsigned* pmx    = (unsigned*)((char*)d_ws + 256 + (size_t)BP * V * 8);
    unsigned* pmy    = pmx + (size_t)BP * V;

    prep_kernel<<<BP, 256, 0, stream>>>(vertices, projmats, maskraw,
                                        nvalid, pts_c, pmx, pmy);
    chamfer_kernel<<<dim3(BP, XROLES + YROLES), TPB, 0, stream>>>(
        edgemaps, elen, nvalid, pts_c, pmx, pmy);
    finalize_kernel<<<B, 256, 0, stream>>>(pmx, pmy, nvalid, elen, out);
}

// Round 4
// 101.833 us; speedup vs baseline: 1.9430x; 1.1156x over previous
//
#include <hip/hip_runtime.h>
#include <stdint.h>

// Problem constants (match reference setup_inputs)
namespace {
constexpr int B = 4, P = 4, V = 4096, M = 2048;
constexpr int BP = B * P;
constexpr float BIGF = 1e10f;
constexpr int TPB   = 256;          // 4 waves per chamfer block
constexpr int OTILE = 128;          // outer points per block (2 per lane)
constexpr int XT = V / OTILE;       // 32 x-role outer tiles
constexpr int YT = M / OTILE;       // 16 y-role outer tiles
constexpr int ROLES = XT + YT;      // 48
constexpr int NBLK = BP * ROLES;    // 768 chamfer blocks (all increment counter)
constexpr int CH = 512;             // inner elems staged per wave-chunk (8 KiB)
}

// workspace offsets (bytes)
//   0    nvalid (16 int)
//   64   sx     (16 float)
//   128  sy     (16 float)
//   192  done counter (1 int)
//   256  pnk (BP*V float4)  packed (x, y, |p|^2, 0) compacted projected pts
//   then epk (BP*M float4)  packed (x, y, |e|^2, 0) edge points

// ---------------------------------------------------------------------------
// prep: detect boundary_mask layout, project+compact masked vertices into
// packed float4 (with norm), pack edgemaps with norms, zero accumulators.
// grid = BP blocks, 256 threads.
// ---------------------------------------------------------------------------
__global__ __launch_bounds__(256) void prep_kernel(
    const float* __restrict__ vertices,    // (B,V,3)
    const float* __restrict__ projmats,    // (P,3,4)
    const uint8_t* __restrict__ maskraw,   // (B,P,V) unknown elem layout
    const float* __restrict__ edgemaps,    // (B,P,M,2)
    int* __restrict__ nvalid,
    float* __restrict__ sx,
    float* __restrict__ sy,
    int* __restrict__ done,
    float4* __restrict__ pnk,              // (BP,V)
    float4* __restrict__ epk)              // (BP,M)
{
    const int bp = blockIdx.x;
    const int b = bp / P, p = bp % P;
    const int tid = threadIdx.x;
    const int lane = tid & 63;

    __shared__ int s_res[4];
    __shared__ int s_cnt;
    if (tid < 4) s_res[tid] = 0;
    if (tid == 0) s_cnt = 0;
    __syncthreads();

    // --- detect mask element layout by byte-residue pattern (mod 4) ---
    // uint8 bernoulli(0.3): nonzero bytes at every residue.
    // int32 0/1 (LE):       nonzero only at residue 0.
    // float32 0/1.0f (LE):  nonzero only at residues 2 (0x80) and 3 (0x3f).
    uint32_t loc[4] = {0u, 0u, 0u, 0u};
    const int NB = 16384;   // 16 KiB prefix: >=4096 elems under every layout
    for (int i = tid * 16; i < NB; i += 256 * 16) {
        const uint32_t* w = (const uint32_t*)(maskraw + i);
        const uint32_t orw = w[0] | w[1] | w[2] | w[3];
        loc[0] |= orw & 0x000000FFu;
        loc[1] |= orw & 0x0000FF00u;
        loc[2] |= orw & 0x00FF0000u;
        loc[3] |= orw & 0xFF000000u;
    }
    #pragma unroll
    for (int j = 0; j < 4; ++j)
        if (loc[j]) atomicOr(&s_res[j], 1);
    __syncthreads();
    int layout;  // 0 = uint8/bool, 1 = int32, 2 = float32
    if (!s_res[1] && !s_res[2] && !s_res[3]) layout = 1;
    else if (!s_res[0] && !s_res[1])         layout = 2;
    else                                      layout = 0;

    // --- pack edgemaps with norms: epk[m] = (ex, ey, |e|^2, 0), all M ---
    const float2* eg = (const float2*)edgemaps + (size_t)bp * M;
    for (int m = tid; m < M; m += 256) {
        const float2 e = eg[m];
        epk[(size_t)bp * M + m] = make_float4(e.x, e.y, fmaf(e.x, e.x, e.y * e.y), 0.f);
    }

    // --- projection matrix for this view (uniform per block) ---
    float mm[12];
    #pragma unroll
    for (int j = 0; j < 12; ++j) mm[j] = projmats[p * 12 + j];

    // --- project + compact masked vertices (ballot-prefix compaction) ---
    for (int v = tid; v < V; v += 256) {
        const int mi = bp * V + v;
        bool msk;
        if (layout == 0)      msk = maskraw[mi] != 0;
        else if (layout == 1) msk = ((const int*)maskraw)[mi] != 0;
        else                  msk = ((const float*)maskraw)[mi] != 0.0f;

        const unsigned long long ball = __ballot(msk);
        const int cnt = __popcll(ball);
        int base = 0;
        if (lane == 0 && cnt) base = atomicAdd(&s_cnt, cnt);
        base = __shfl(base, 0, 64);
        if (msk) {
            const float x = vertices[(b * V + v) * 3 + 0];
            const float y = vertices[(b * V + v) * 3 + 1];
            const float z = vertices[(b * V + v) * 3 + 2];
            const float u  = mm[0]*x + mm[1]*y + mm[2]*z  + mm[3];
            const float vv = mm[4]*x + mm[5]*y + mm[6]*z  + mm[7];
            const float w  = mm[8]*x + mm[9]*y + mm[10]*z + mm[11];
            const int off = __popcll(ball & ((1ull << lane) - 1ull));
            const float rw = 1.0f / w;
            const float px = u * rw, py = vv * rw;
            pnk[(size_t)bp * V + base + off] =
                make_float4(px, py, fmaf(px, px, py * py), 0.f);
        }
    }
    __syncthreads();
    if (tid == 0) {
        nvalid[bp] = s_cnt;
        sx[bp] = 0.0f;
        sy[bp] = 0.0f;
        if (bp == 0) *done = 0;
    }
}

// ---------------------------------------------------------------------------
// chamfer (fused finalize): block owns 128 outer points; its 4 waves split
// the inner range, each staging wave-local LDS chunks (no barriers in hot
// loop), d2 = (|e|^2 - 2e.p) + |p|^2 -> 3 VALU/pair/chain.  Partial mins
// merged via 2 KiB LDS, one atomicAdd per block.  Last block (done counter)
// computes out[b].  grid = (BP, ROLES), 256 threads.
// ---------------------------------------------------------------------------
__global__ __launch_bounds__(TPB) void chamfer_kernel(
    const int* __restrict__ elen,          // (B,P)
    int* __restrict__ nvalid,
    float* __restrict__ sx,
    float* __restrict__ sy,
    int* __restrict__ done,
    const float4* __restrict__ pnk,        // (BP,V)
    const float4* __restrict__ epk,        // (BP,M)
    float* __restrict__ out)               // (B)
{
    const int bp   = blockIdx.x;
    const int role = blockIdx.y;
    const int tid  = threadIdx.x;
    const int wave = tid >> 6;
    const int lane = tid & 63;
    const int len  = elen[bp];
    const int nv   = nvalid[bp];

    __shared__ float4 sb[4][CH];       // 32 KiB wave-private staging
    __shared__ float  smin[4][OTILE];  // 2 KiB merge buffer
    __shared__ int    s_last;

    const float4* outer; const float4* inner;
    int lim, L, obase;
    float* acc;
    const bool isX = (role < XT);
    if (isX) {
        obase = role * OTILE;
        outer = pnk + (size_t)bp * V;  lim = nv;
        inner = epk + (size_t)bp * M;  L = len;
        acc = &sx[bp];
    } else {
        obase = (role - XT) * OTILE;
        outer = epk + (size_t)bp * M;  lim = len;
        inner = pnk + (size_t)bp * V;  L = nv;
        acc = &sy[bp];
    }
    const bool active = (obase < lim);   // block-uniform

    float pn0 = 0.f, pn1 = 0.f;
    if (active) {
        // my 2 outer points (same set for all 4 waves)
        const float4 p0 = outer[obase + lane];
        const float4 p1 = outer[obase + 64 + lane];
        const float a0 = -2.0f * p0.x, b0 = -2.0f * p0.y;  pn0 = p0.z;
        const float a1 = -2.0f * p1.x, b1 = -2.0f * p1.y;  pn1 = p1.z;

        // wave-private inner range [s,e)
        const int q = (L + 3) >> 2;
        const int is = wave * q;
        const int ie = min(is + q, L);
        float4* sbw = sb[wave];

        float mn0 = BIGF, mn1 = BIGF;
        for (int cs = is; cs < ie; cs += CH) {
            const int cnt  = min(CH, ie - cs);
            const int cnt8 = (cnt + 7) & ~7;
            for (int j = lane; j < cnt; j += 64) sbw[j] = inner[cs + j];
            for (int j = cnt + lane; j < cnt8; j += 64)
                sbw[j] = make_float4(0.f, 0.f, BIGF, 0.f);   // exact no-op pad
            // wave-local RAW: compiler inserts lgkmcnt waits, no barrier
            #pragma unroll 8
            for (int j = 0; j < cnt8; ++j) {
                const float4 t = sbw[j];           // wave-uniform broadcast
                mn0 = fminf(mn0, fmaf(t.x, a0, fmaf(t.y, b0, t.z)));
                mn1 = fminf(mn1, fmaf(t.x, a1, fmaf(t.y, b1, t.z)));
            }
        }
        smin[wave][lane]      = mn0;
        smin[wave][64 + lane] = mn1;
    }
    __syncthreads();                       // 'active' is block-uniform
    if (active && wave == 0) {
        const float m0 = fminf(fminf(smin[0][lane],      smin[1][lane]),
                               fminf(smin[2][lane],      smin[3][lane]));
        const float m1 = fminf(fminf(smin[0][64 + lane], smin[1][64 + lane]),
                               fminf(smin[2][64 + lane], smin[3][64 + lane]));
        float val = 0.0f;
        if (obase + lane < lim)      val += fmaxf(m0 + pn0, 0.0f);
        if (obase + 64 + lane < lim) val += fmaxf(m1 + pn1, 0.0f);
        #pragma unroll
        for (int off = 32; off > 0; off >>= 1)
            val += __shfl_down(val, off, 64);
        if (lane == 0) atomicAdd(acc, val);
    }

    // done-counter: every block increments exactly once; last block finalizes
    __syncthreads();
    if (tid == 0) {
        __threadfence();                               // release our adds
        const int old = atomicAdd(done, 1);
        s_last = (old == NBLK - 1) ? 1 : 0;
    }
    __syncthreads();
    if (s_last) {
        __threadfence();                               // acquire others' adds
        if (tid < B) {
            float o = 0.0f;
            #pragma unroll
            for (int p = 0; p < P; ++p) {
                const int j = tid * P + p;
                o += sx[j] / fmaxf((float)nvalid[j], 1.0f)
                   + sy[j] / fmaxf((float)elen[j], 1.0f);
            }
            out[tid] = o * (1.0f / P);
        }
    }
}

extern "C" void kernel_launch(void* const* d_in, const int* in_sizes, int n_in,
                              void* d_out, int out_size, void* d_ws, size_t ws_size,
                              hipStream_t stream)
{
    const float*   vertices = (const float*)d_in[0];
    const float*   projmats = (const float*)d_in[1];
    const float*   edgemaps = (const float*)d_in[2];
    const uint8_t* maskraw  = (const uint8_t*)d_in[3];
    const int*     elen     = (const int*)d_in[4];
    float* out = (float*)d_out;

    char* ws = (char*)d_ws;
    int*    nvalid = (int*)(ws + 0);
    float*  sx     = (float*)(ws + 64);
    float*  sy     = (float*)(ws + 128);
    int*    done   = (int*)(ws + 192);
    float4* pnk    = (float4*)(ws + 256);
    float4* epk    = pnk + (size_t)BP * V;

    prep_kernel<<<BP, 256, 0, stream>>>(vertices, projmats, maskraw, edgemaps,
                                        nvalid, sx, sy, done, pnk, epk);
    chamfer_kernel<<<dim3(BP, ROLES), TPB, 0, stream>>>(elen, nvalid, sx, sy,
                                                        done, pnk, epk, out);
}

// Round 5
// 93.642 us; speedup vs baseline: 2.1130x; 1.0875x over previous
//
#include <hip/hip_runtime.h>
#include <stdint.h>

// Problem constants (match reference setup_inputs)
namespace {
constexpr int B = 4, P = 4, V = 4096, M = 2048;
constexpr int BP = B * P;
constexpr float BIGF = 1e10f;
constexpr int TPB   = 256;          // 4 waves per chamfer block
constexpr int OTILE = 128;          // outer points per block (2 per lane)
constexpr int XT = V / OTILE;       // 32 x-role outer tiles
constexpr int YT = M / OTILE;       // 16 y-role outer tiles
constexpr int ROLES = XT + YT;      // 48
constexpr int NBLK = BP * ROLES;    // 768 chamfer blocks (all increment counter)
constexpr int CH = 512;             // inner elems staged per wave-chunk (8 KiB)
constexpr int KPB = 4;              // prep blocks per (b,p)
constexpr int VPB = V / KPB;        // 1024 vertices per prep block
constexpr int MPB = M / KPB;        // 512 edgemap elems per prep block
}

// workspace offsets (bytes)
//   0    nvalid (16 int)
//   64   sx     (16 float)
//   128  sy     (16 float)
//   192  done counter (1 int)
//   256  pnk (BP*V float4)  packed (x, y, |p|^2, 0) compacted projected pts
//   then epk (BP*M float4)  packed (x, y, |e|^2, 0) edge points

// ---------------------------------------------------------------------------
// prep: 4 blocks per (b,p). Each block detects the mask layout, popcounts the
// mask prefix of earlier chunks to get its deterministic compaction base (no
// cross-block atomics), projects+compacts its 1024 vertices, packs its 512
// edgemap elems with norms. Last chunk-block writes nvalid; chunk-0 blocks
// zero the accumulators.  grid = BP*KPB blocks, 256 threads.
// ---------------------------------------------------------------------------
__global__ __launch_bounds__(256) void prep_kernel(
    const float* __restrict__ vertices,    // (B,V,3)
    const float* __restrict__ projmats,    // (P,3,4)
    const uint8_t* __restrict__ maskraw,   // (B,P,V) unknown elem layout
    const float* __restrict__ edgemaps,    // (B,P,M,2)
    int* __restrict__ nvalid,
    float* __restrict__ sx,
    float* __restrict__ sy,
    int* __restrict__ done,
    float4* __restrict__ pnk,              // (BP,V)
    float4* __restrict__ epk)              // (BP,M)
{
    const int bp = blockIdx.x / KPB;
    const int k  = blockIdx.x % KPB;
    const int b = bp / P, p = bp % P;
    const int tid = threadIdx.x;
    const int lane = tid & 63;
    const int wave = tid >> 6;

    __shared__ int s_res[4];
    __shared__ int s_cnt;
    __shared__ int s_prew[4];
    if (tid < 4) { s_res[tid] = 0; s_prew[tid] = 0; }
    if (tid == 0) s_cnt = 0;
    __syncthreads();

    // --- detect mask element layout by byte-residue pattern (mod 4) ---
    // uint8 bernoulli(0.3): nonzero bytes at every residue.
    // int32 0/1 (LE):       nonzero only at residue 0.
    // float32 0/1.0f (LE):  nonzero only at residues 2 (0x80) and 3 (0x3f).
    uint32_t loc[4] = {0u, 0u, 0u, 0u};
    const int NB = 16384;   // 16 KiB prefix: >=4096 elems under every layout
    for (int i = tid * 16; i < NB; i += 256 * 16) {
        const uint32_t* w = (const uint32_t*)(maskraw + i);
        const uint32_t orw = w[0] | w[1] | w[2] | w[3];
        loc[0] |= orw & 0x000000FFu;
        loc[1] |= orw & 0x0000FF00u;
        loc[2] |= orw & 0x00FF0000u;
        loc[3] |= orw & 0xFF000000u;
    }
    #pragma unroll
    for (int j = 0; j < 4; ++j)
        if (loc[j]) atomicOr(&s_res[j], 1);
    __syncthreads();
    int layout;  // 0 = uint8/bool, 1 = int32, 2 = float32
    if (!s_res[1] && !s_res[2] && !s_res[3]) layout = 1;
    else if (!s_res[0] && !s_res[1])         layout = 2;
    else                                      layout = 0;

    // --- pack my edgemap quarter with norms ---
    {
        const float2* eg = (const float2*)edgemaps + (size_t)bp * M;
        for (int m = k * MPB + tid; m < (k + 1) * MPB; m += 256) {
            const float2 e = eg[m];
            epk[(size_t)bp * M + m] =
                make_float4(e.x, e.y, fmaf(e.x, e.x, e.y * e.y), 0.f);
        }
    }

    // --- popcount mask prefix [0, k*VPB) -> deterministic compaction base ---
    const int pre_n = k * VPB;
    int cnt = 0;
    if (layout == 0) {
        const uint8_t* mk = maskraw + (size_t)bp * V;
        for (int i = tid; i < pre_n; i += 256) cnt += (mk[i] != 0);
    } else if (layout == 1) {
        const int* mk = (const int*)maskraw + (size_t)bp * V;
        for (int i = tid; i < pre_n; i += 256) cnt += (mk[i] != 0);
    } else {
        const float* mk = (const float*)maskraw + (size_t)bp * V;
        for (int i = tid; i < pre_n; i += 256) cnt += (mk[i] != 0.0f);
    }
    #pragma unroll
    for (int off = 32; off > 0; off >>= 1) cnt += __shfl_down(cnt, off, 64);
    if (lane == 0) s_prew[wave] = cnt;
    __syncthreads();
    const int pre_total = s_prew[0] + s_prew[1] + s_prew[2] + s_prew[3];

    // --- projection matrix for this view (uniform per block) ---
    float mm[12];
    #pragma unroll
    for (int j = 0; j < 12; ++j) mm[j] = projmats[p * 12 + j];

    // --- project + compact my 1024 vertices (ballot-prefix compaction) ---
    for (int v = k * VPB + tid; v < (k + 1) * VPB; v += 256) {
        const int mi = bp * V + v;
        bool msk;
        if (layout == 0)      msk = maskraw[mi] != 0;
        else if (layout == 1) msk = ((const int*)maskraw)[mi] != 0;
        else                  msk = ((const float*)maskraw)[mi] != 0.0f;

        const unsigned long long ball = __ballot(msk);
        const int bcnt = __popcll(ball);
        int base = 0;
        if (lane == 0 && bcnt) base = atomicAdd(&s_cnt, bcnt);
        base = __shfl(base, 0, 64);
        if (msk) {
            const float x = vertices[(b * V + v) * 3 + 0];
            const float y = vertices[(b * V + v) * 3 + 1];
            const float z = vertices[(b * V + v) * 3 + 2];
            const float u  = mm[0]*x + mm[1]*y + mm[2]*z  + mm[3];
            const float vv = mm[4]*x + mm[5]*y + mm[6]*z  + mm[7];
            const float w  = mm[8]*x + mm[9]*y + mm[10]*z + mm[11];
            const int off = __popcll(ball & ((1ull << lane) - 1ull));
            const float rw = 1.0f / w;
            const float px = u * rw, py = vv * rw;
            pnk[(size_t)bp * V + pre_total + base + off] =
                make_float4(px, py, fmaf(px, px, py * py), 0.f);
        }
    }
    __syncthreads();
    if (tid == 0) {
        if (k == KPB - 1) nvalid[bp] = pre_total + s_cnt;
        if (k == 0) { sx[bp] = 0.0f; sy[bp] = 0.0f; }
        if (blockIdx.x == 0) *done = 0;
    }
}

// ---------------------------------------------------------------------------
// chamfer (fused finalize): block owns 128 outer points; its 4 waves split
// the inner range, each staging wave-local LDS chunks (no barriers in hot
// loop), d2 = (|e|^2 - 2e.p) + |p|^2 -> 3 VALU/pair/chain.  Partial mins
// merged via 2 KiB LDS, one atomicAdd per block.  Last block (done counter)
// computes out[b].  grid = (BP, ROLES), 256 threads.
// ---------------------------------------------------------------------------
__global__ __launch_bounds__(TPB) void chamfer_kernel(
    const int* __restrict__ elen,          // (B,P)
    int* __restrict__ nvalid,
    float* __restrict__ sx,
    float* __restrict__ sy,
    int* __restrict__ done,
    const float4* __restrict__ pnk,        // (BP,V)
    const float4* __restrict__ epk,        // (BP,M)
    float* __restrict__ out)               // (B)
{
    const int bp   = blockIdx.x;
    const int role = blockIdx.y;
    const int tid  = threadIdx.x;
    const int wave = tid >> 6;
    const int lane = tid & 63;
    const int len  = elen[bp];
    const int nv   = nvalid[bp];

    __shared__ float4 sb[4][CH];       // 32 KiB wave-private staging
    __shared__ float  smin[4][OTILE];  // 2 KiB merge buffer
    __shared__ int    s_last;

    const float4* outer; const float4* inner;
    int lim, L, obase;
    float* acc;
    const bool isX = (role < XT);
    if (isX) {
        obase = role * OTILE;
        outer = pnk + (size_t)bp * V;  lim = nv;
        inner = epk + (size_t)bp * M;  L = len;
        acc = &sx[bp];
    } else {
        obase = (role - XT) * OTILE;
        outer = epk + (size_t)bp * M;  lim = len;
        inner = pnk + (size_t)bp * V;  L = nv;
        acc = &sy[bp];
    }
    const bool active = (obase < lim);   // block-uniform

    float pn0 = 0.f, pn1 = 0.f;
    if (active) {
        // my 2 outer points (same set for all 4 waves)
        const float4 p0 = outer[obase + lane];
        const float4 p1 = outer[obase + 64 + lane];
        const float a0 = -2.0f * p0.x, b0 = -2.0f * p0.y;  pn0 = p0.z;
        const float a1 = -2.0f * p1.x, b1 = -2.0f * p1.y;  pn1 = p1.z;

        // wave-private inner range [s,e)
        const int q = (L + 3) >> 2;
        const int is = wave * q;
        const int ie = min(is + q, L);
        float4* sbw = sb[wave];

        float mn0 = BIGF, mn1 = BIGF;
        for (int cs = is; cs < ie; cs += CH) {
            const int cnt  = min(CH, ie - cs);
            const int cnt8 = (cnt + 7) & ~7;
            for (int j = lane; j < cnt; j += 64) sbw[j] = inner[cs + j];
            for (int j = cnt + lane; j < cnt8; j += 64)
                sbw[j] = make_float4(0.f, 0.f, BIGF, 0.f);   // exact no-op pad
            // wave-local RAW: compiler inserts lgkmcnt waits, no barrier
            #pragma unroll 8
            for (int j = 0; j < cnt8; ++j) {
                const float4 t = sbw[j];           // wave-uniform broadcast
                mn0 = fminf(mn0, fmaf(t.x, a0, fmaf(t.y, b0, t.z)));
                mn1 = fminf(mn1, fmaf(t.x, a1, fmaf(t.y, b1, t.z)));
            }
        }
        smin[wave][lane]      = mn0;
        smin[wave][64 + lane] = mn1;
    }
    __syncthreads();                       // 'active' is block-uniform
    if (active && wave == 0) {
        const float m0 = fminf(fminf(smin[0][lane],      smin[1][lane]),
                               fminf(smin[2][lane],      smin[3][lane]));
        const float m1 = fminf(fminf(smin[0][64 + lane], smin[1][64 + lane]),
                               fminf(smin[2][64 + lane], smin[3][64 + lane]));
        float val = 0.0f;
        if (obase + lane < lim)      val += fmaxf(m0 + pn0, 0.0f);
        if (obase + 64 + lane < lim) val += fmaxf(m1 + pn1, 0.0f);
        #pragma unroll
        for (int off = 32; off > 0; off >>= 1)
            val += __shfl_down(val, off, 64);
        if (lane == 0) atomicAdd(acc, val);
    }

    // done-counter: every block increments exactly once; last block finalizes
    __syncthreads();
    if (tid == 0) {
        __threadfence();                               // release our adds
        const int old = atomicAdd(done, 1);
        s_last = (old == NBLK - 1) ? 1 : 0;
    }
    __syncthreads();
    if (s_last) {
        __threadfence();                               // acquire others' adds
        if (tid < B) {
            float o = 0.0f;
            #pragma unroll
            for (int p = 0; p < P; ++p) {
                const int j = tid * P + p;
                o += sx[j] / fmaxf((float)nvalid[j], 1.0f)
                   + sy[j] / fmaxf((float)elen[j], 1.0f);
            }
            out[tid] = o * (1.0f / P);
        }
    }
}

extern "C" void kernel_launch(void* const* d_in, const int* in_sizes, int n_in,
                              void* d_out, int out_size, void* d_ws, size_t ws_size,
                              hipStream_t stream)
{
    const float*   vertices = (const float*)d_in[0];
    const float*   projmats = (const float*)d_in[1];
    const float*   edgemaps = (const float*)d_in[2];
    const uint8_t* maskraw  = (const uint8_t*)d_in[3];
    const int*     elen     = (const int*)d_in[4];
    float* out = (float*)d_out;

    char* ws = (char*)d_ws;
    int*    nvalid = (int*)(ws + 0);
    float*  sx     = (float*)(ws + 64);
    float*  sy     = (float*)(ws + 128);
    int*    done   = (int*)(ws + 192);
    float4* pnk    = (float4*)(ws + 256);
    float4* epk    = pnk + (size_t)BP * V;

    prep_kernel<<<BP * KPB, 256, 0, stream>>>(vertices, projmats, maskraw,
                                              edgemaps, nvalid, sx, sy, done,
                                              pnk, epk);
    chamfer_kernel<<<dim3(BP, ROLES), TPB, 0, stream>>>(elen, nvalid, sx, sy,
                                                        done, pnk, epk, out);
}